// Round 4
// baseline (769.119 us; speedup 1.0000x reference)
//
#include <hip/hip_runtime.h>
#include <hip/hip_bf16.h>

// Grouped-dequant GEMM: Y[m,o] = sum_k X[m,k] * W[o,k] * S[o, k/128] + bias[o]
// M=8192, N=O=4096, K=I=4096, G=128.
// HARNESS DTYPES (deduced R0-R3): fp16 tensors are promoted to FLOAT32 on both
// inputs and output. Kernel converts x/W to bf16 (RNE) and runs the 128x128
// bf16 MFMA tile (BK=64, 4 waves 2x2, 4x4 mfma_f32_16x16x32_bf16 frags).
// Path A (ws big enough): separate convert kernel -> bf16 GEMM (VALU-lean loop).
// Path B: convert inline during staging. Dequant = telescoping acc rescale.

typedef short bf16x8 __attribute__((ext_vector_type(8)));
typedef float f32x4 __attribute__((ext_vector_type(4)));
typedef int   i32x4 __attribute__((ext_vector_type(4)));

#define BM 128
#define BN 128
#define BK 64

__device__ __forceinline__ unsigned pk_bf16_rne(float x, float y) {
    unsigned a = __float_as_uint(x), b = __float_as_uint(y);
    a = a + 0x7FFFu + ((a >> 16) & 1u);          // round-to-nearest-even
    b = b + 0x7FFFu + ((b >> 16) & 1u);
    return (b & 0xFFFF0000u) | (a >> 16);        // [lo=bf16(x), hi=bf16(y)]
}

// ---- Path A: f32 -> bf16 bulk convert (grid-stride, 8 f32 -> 16B per thread) ----
__global__ __launch_bounds__(256) void cvt_f32_bf16(
    const float* __restrict__ src, unsigned short* __restrict__ dst, long n)
{
    long i = (long)(blockIdx.x) * blockDim.x + threadIdx.x;   // in units of 8 elts
    const long n8 = n >> 3;
    const long stride = (long)gridDim.x * blockDim.x;
    for (; i < n8; i += stride) {
        f32x4 a = *(const f32x4*)(src + i * 8);
        f32x4 b = *(const f32x4*)(src + i * 8 + 4);
        i32x4 o;
        o.x = pk_bf16_rne(a.x, a.y);
        o.y = pk_bf16_rne(a.z, a.w);
        o.z = pk_bf16_rne(b.x, b.y);
        o.w = pk_bf16_rne(b.z, b.w);
        *(i32x4*)(dst + i * 8) = o;
    }
}

// ---- GEMM: F32IN=true reads f32 X/W and converts inline; false reads bf16 bits ----
template <bool F32IN>
__global__ __launch_bounds__(256) void gq_gemm(
    const void* __restrict__ Xv,     // M x K  (f32 or bf16 bits)
    const void* __restrict__ Wv,     // N x K
    const float* __restrict__ S,     // N x (K/128)
    const float* __restrict__ Bv,    // N
    float* __restrict__ Y,           // M x N  (f32)
    int M, int N, int K)
{
    __shared__ short As[BM * BK];    // row-major [row][64], bf16 bits
    __shared__ short Bs[BN * BK];

    const int tid  = threadIdx.x;
    const int wave = tid >> 6;
    const int lane = tid & 63;
    const int wm   = wave >> 1;
    const int wn   = wave & 1;
    const int l15  = lane & 15;
    const int quad = lane >> 4;

    const int nTilesN = N / BN;
    const int bm = blockIdx.x / nTilesN;
    const int bn = blockIdx.x % nTilesN;
    const int rowBase = bm * BM;
    const int colBase = bn * BN;

    // staging: thread t -> row t>>3 (+32/pass), col (t&7)*8 elements
    const int srow = tid >> 3;
    const int scol = (tid & 7) * 8;

    const int groups = K >> 7;

    f32x4 acc[4][4];
    #pragma unroll
    for (int i = 0; i < 4; ++i)
        #pragma unroll
        for (int j = 0; j < 4; ++j)
            acc[i][j] = (f32x4){0.f, 0.f, 0.f, 0.f};

    float t_prev[4] = {1.f, 1.f, 1.f, 1.f};

    for (int k0 = 0; k0 < K; k0 += BK) {
        // ---- global loads into registers (overlap prev tile's MFMAs) ----
        i32x4 ra[4], rb[4];
        #pragma unroll
        for (int i = 0; i < 4; ++i) {
            const int row = i * 32 + srow;
            if (F32IN) {
                const float* gA = (const float*)Xv + (size_t)(rowBase + row) * K + (k0 + scol);
                const float* gB = (const float*)Wv + (size_t)(colBase + row) * K + (k0 + scol);
                f32x4 a0 = *(const f32x4*)gA, a1 = *(const f32x4*)(gA + 4);
                f32x4 b0 = *(const f32x4*)gB, b1 = *(const f32x4*)(gB + 4);
                ra[i].x = pk_bf16_rne(a0.x, a0.y); ra[i].y = pk_bf16_rne(a0.z, a0.w);
                ra[i].z = pk_bf16_rne(a1.x, a1.y); ra[i].w = pk_bf16_rne(a1.z, a1.w);
                rb[i].x = pk_bf16_rne(b0.x, b0.y); rb[i].y = pk_bf16_rne(b0.z, b0.w);
                rb[i].z = pk_bf16_rne(b1.x, b1.y); rb[i].w = pk_bf16_rne(b1.z, b1.w);
            } else {
                const unsigned short* gA = (const unsigned short*)Xv + (size_t)(rowBase + row) * K + (k0 + scol);
                const unsigned short* gB = (const unsigned short*)Wv + (size_t)(colBase + row) * K + (k0 + scol);
                ra[i] = *(const i32x4*)gA;
                rb[i] = *(const i32x4*)gB;
            }
        }

        // ---- group boundary: telescoping rescale acc *= t_prev / t_cur ----
        if ((k0 & 127) == 0) {
            const int g = k0 >> 7;
            float r[4];
            #pragma unroll
            for (int nt = 0; nt < 4; ++nt) {
                const int o = colBase + wn * 64 + nt * 16 + l15;
                const float t_cur = S[(size_t)o * groups + g];
                r[nt] = t_prev[nt] / t_cur;
                t_prev[nt] = t_cur;
            }
            #pragma unroll
            for (int mt = 0; mt < 4; ++mt)
                #pragma unroll
                for (int nt = 0; nt < 4; ++nt)
                    #pragma unroll
                    for (int e = 0; e < 4; ++e)
                        acc[mt][nt][e] *= r[nt];
        }

        __syncthreads();            // all waves done reading prev tile

        #pragma unroll
        for (int i = 0; i < 4; ++i) {
            const int row = i * 32 + srow;
            *(i32x4*)&As[row * BK + scol] = ra[i];
            *(i32x4*)&Bs[row * BK + scol] = rb[i];
        }

        __syncthreads();            // tile visible

        // ---- 2 k-steps of 32, 16 MFMAs each ----
        #pragma unroll
        for (int ks = 0; ks < 2; ++ks) {
            const int kb = ks * 32 + quad * 8;
            bf16x8 a[4], b[4];
            #pragma unroll
            for (int t = 0; t < 4; ++t)
                a[t] = *(const bf16x8*)&As[(wm * 64 + t * 16 + l15) * BK + kb];
            #pragma unroll
            for (int t = 0; t < 4; ++t)
                b[t] = *(const bf16x8*)&Bs[(wn * 64 + t * 16 + l15) * BK + kb];
            #pragma unroll
            for (int mt = 0; mt < 4; ++mt)
                #pragma unroll
                for (int nt = 0; nt < 4; ++nt)
                    acc[mt][nt] = __builtin_amdgcn_mfma_f32_16x16x32_bf16(
                        a[mt], b[nt], acc[mt][nt], 0, 0, 0);
        }
    }

    // ---- epilogue: Y = acc * t_last + bias (f32 store) ----
    #pragma unroll
    for (int nt = 0; nt < 4; ++nt) {
        const int col = colBase + wn * 64 + nt * 16 + l15;
        const float tl = t_prev[nt];
        const float bf = Bv[col];
        #pragma unroll
        for (int mt = 0; mt < 4; ++mt) {
            const int row0 = rowBase + wm * 64 + mt * 16 + quad * 4;
            #pragma unroll
            for (int r = 0; r < 4; ++r)
                Y[(size_t)(row0 + r) * N + col] = acc[mt][nt][r] * tl + bf;
        }
    }
}

extern "C" void kernel_launch(void* const* d_in, const int* in_sizes, int n_in,
                              void* d_out, int out_size, void* d_ws, size_t ws_size,
                              hipStream_t stream) {
    const float* X  = (const float*)d_in[0];   // x      (B,S,I)  f32 (fp16 promoted)
    const float* W  = (const float*)d_in[1];   // weight (O,I)
    const float* S  = (const float*)d_in[2];   // scales (O,I/G)
    const float* Bv = (const float*)d_in[3];   // bias   (O,)
    float* Y = (float*)d_out;

    const int O = in_sizes[3];                 // 4096
    const int K = in_sizes[1] / O;             // 4096
    const int M = in_sizes[0] / K;             // 8192

    const dim3 grid((M / BM) * (O / BN));
    const size_t nX = (size_t)M * K, nW = (size_t)O * K;
    const size_t wsNeeded = (nX + nW) * sizeof(unsigned short);

    if (ws_size >= wsNeeded) {
        // Path A: bulk convert to bf16 in d_ws, then VALU-lean bf16 GEMM
        unsigned short* Xb = (unsigned short*)d_ws;
        unsigned short* Wb = Xb + nX;
        cvt_f32_bf16<<<4096, 256, 0, stream>>>(X, Xb, (long)nX);
        cvt_f32_bf16<<<2048, 256, 0, stream>>>(W, Wb, (long)nW);
        gq_gemm<false><<<grid, 256, 0, stream>>>(Xb, Wb, S, Bv, Y, M, O, K);
    } else {
        // Path B: convert inline during staging
        gq_gemm<true><<<grid, 256, 0, stream>>>(X, W, S, Bv, Y, M, O, K);
    }
}

// Round 5
// 733.009 us; speedup vs baseline: 1.0493x; 1.0493x over previous
//
#include <hip/hip_runtime.h>
#include <hip/hip_bf16.h>

// Grouped-dequant GEMM: Y[m,o] = sum_k X[m,k] * W[o,k] * S[o, k/128] + bias[o]
// M=8192, N=O=4096, K=I=4096, G=128. Harness promotes fp16 tensors to f32
// (inputs AND output) — verified R4 (absmax 0.125 = 1 bf16 ulp).
// Path A: f32->bf16 bulk convert into d_ws, then m97-structure GEMM:
// 128x128 tile, BK=64, 4 waves (2x2), 4x4 mfma_f32_16x16x32_bf16 frags,
// global_load_lds width=16 staging (no ds_write -> kills the 1e8 bank-conflict
// cycles seen in R4). Dequant folded via telescoping accumulator rescale.

typedef short bf16x8 __attribute__((ext_vector_type(8)));
typedef float f32x4 __attribute__((ext_vector_type(4)));
typedef int   i32x4 __attribute__((ext_vector_type(4)));

#define BM 128
#define BN 128
#define BK 64

__device__ __forceinline__ unsigned pk_bf16_rne(float x, float y) {
    unsigned a = __float_as_uint(x), b = __float_as_uint(y);
    a = a + 0x7FFFu + ((a >> 16) & 1u);          // round-to-nearest-even
    b = b + 0x7FFFu + ((b >> 16) & 1u);
    return (b & 0xFFFF0000u) | (a >> 16);        // [lo=bf16(x), hi=bf16(y)]
}

// ---- f32 -> bf16 bulk convert (8 f32 -> 16B per thread) ----
__global__ __launch_bounds__(256) void cvt_f32_bf16(
    const float* __restrict__ src, unsigned short* __restrict__ dst, long n)
{
    long i = (long)(blockIdx.x) * blockDim.x + threadIdx.x;   // units of 8 elts
    const long n8 = n >> 3;
    const long stride = (long)gridDim.x * blockDim.x;
    for (; i < n8; i += stride) {
        f32x4 a = *(const f32x4*)(src + i * 8);
        f32x4 b = *(const f32x4*)(src + i * 8 + 4);
        i32x4 o;
        o.x = pk_bf16_rne(a.x, a.y);
        o.y = pk_bf16_rne(a.z, a.w);
        o.z = pk_bf16_rne(b.x, b.y);
        o.w = pk_bf16_rne(b.z, b.w);
        *(i32x4*)(dst + i * 8) = o;
    }
}

// ---- Path A GEMM: bf16 inputs, global_load_lds staging (m97 structure) ----
__global__ __launch_bounds__(256) void gq_gemm_lds(
    const unsigned short* __restrict__ X,    // M x K  bf16 bits
    const unsigned short* __restrict__ W,    // N x K  bf16 bits
    const float* __restrict__ S,             // N x (K/128)
    const float* __restrict__ Bv,            // N
    float* __restrict__ Y,                   // M x N  f32
    int M, int N, int K)
{
    __shared__ short As[BM * BK];   // row-major [row][64], unpadded (DMA layout)
    __shared__ short Bs[BN * BK];

    const int tid  = threadIdx.x;
    const int wave = tid >> 6;
    const int lane = tid & 63;
    const int wm   = wave >> 1;
    const int wn   = wave & 1;
    const int l15  = lane & 15;
    const int quad = lane >> 4;

    const int nTilesN = N / BN;
    const int bm = blockIdx.x / nTilesN;
    const int bn = blockIdx.x % nTilesN;
    const int rowBase = bm * BM;
    const int colBase = bn * BN;

    // staging: lane l -> row offset l>>3, col (l&7)*8 shorts (16B); DMA writes
    // wave-uniform LDS base + lane*16B, which lands lane l at exactly that slot.
    const int lrow = lane >> 3;
    const int lcol = (lane & 7) * 8;

    const int groups = K >> 7;

    f32x4 acc[4][4];
    #pragma unroll
    for (int i = 0; i < 4; ++i)
        #pragma unroll
        for (int j = 0; j < 4; ++j)
            acc[i][j] = (f32x4){0.f, 0.f, 0.f, 0.f};

    float t_prev[4] = {1.f, 1.f, 1.f, 1.f};

    for (int k0 = 0; k0 < K; k0 += BK) {
        __syncthreads();            // all waves done reading prev tile's LDS

        // ---- stage A and B tiles via direct-to-LDS DMA: 4 issues each ----
        #pragma unroll
        for (int i = 0; i < 4; ++i) {
            const int row = i * 32 + wave * 8 + lrow;
            const unsigned short* gA = X + (size_t)(rowBase + row) * K + (k0 + lcol);
            const unsigned short* gB = W + (size_t)(colBase + row) * K + (k0 + lcol);
            short* lA = &As[(i * 32 + wave * 8) * BK];   // wave-uniform base
            short* lB = &Bs[(i * 32 + wave * 8) * BK];
            __builtin_amdgcn_global_load_lds(
                (const __attribute__((address_space(1))) void*)gA,
                (__attribute__((address_space(3))) void*)lA, 16, 0, 0);
            __builtin_amdgcn_global_load_lds(
                (const __attribute__((address_space(1))) void*)gB,
                (__attribute__((address_space(3))) void*)lB, 16, 0, 0);
        }

        // ---- group boundary: telescoping rescale acc *= t_prev / t_cur ----
        if ((k0 & 127) == 0) {
            const int g = k0 >> 7;
            float r[4];
            #pragma unroll
            for (int nt = 0; nt < 4; ++nt) {
                const int o = colBase + wn * 64 + nt * 16 + l15;
                const float t_cur = S[(size_t)o * groups + g];
                r[nt] = t_prev[nt] / t_cur;
                t_prev[nt] = t_cur;
            }
            #pragma unroll
            for (int mt = 0; mt < 4; ++mt)
                #pragma unroll
                for (int nt = 0; nt < 4; ++nt)
                    #pragma unroll
                    for (int e = 0; e < 4; ++e)
                        acc[mt][nt][e] *= r[nt];
        }

        __syncthreads();            // barrier's vmcnt(0) drains the DMA

        // ---- compute: 2 k-steps of 32, 16 MFMAs each ----
        #pragma unroll
        for (int ks = 0; ks < 2; ++ks) {
            const int kb = ks * 32 + quad * 8;
            bf16x8 a[4], b[4];
            #pragma unroll
            for (int t = 0; t < 4; ++t)
                a[t] = *(const bf16x8*)&As[(wm * 64 + t * 16 + l15) * BK + kb];
            #pragma unroll
            for (int t = 0; t < 4; ++t)
                b[t] = *(const bf16x8*)&Bs[(wn * 64 + t * 16 + l15) * BK + kb];
            #pragma unroll
            for (int mt = 0; mt < 4; ++mt)
                #pragma unroll
                for (int nt = 0; nt < 4; ++nt)
                    acc[mt][nt] = __builtin_amdgcn_mfma_f32_16x16x32_bf16(
                        a[mt], b[nt], acc[mt][nt], 0, 0, 0);
        }
    }

    // ---- epilogue: Y = acc * t_last + bias ----
    #pragma unroll
    for (int nt = 0; nt < 4; ++nt) {
        const int col = colBase + wn * 64 + nt * 16 + l15;
        const float tl = t_prev[nt];
        const float bf = Bv[col];
        #pragma unroll
        for (int mt = 0; mt < 4; ++mt) {
            const int row0 = rowBase + wm * 64 + mt * 16 + quad * 4;
            #pragma unroll
            for (int r = 0; r < 4; ++r)
                Y[(size_t)(row0 + r) * N + col] = acc[mt][nt][r] * tl + bf;
        }
    }
}

// ---- Path B fallback: f32 inputs converted inline, explicit ds_write staging ----
__global__ __launch_bounds__(256) void gq_gemm_f32in(
    const float* __restrict__ Xf, const float* __restrict__ Wf,
    const float* __restrict__ S, const float* __restrict__ Bv,
    float* __restrict__ Y, int M, int N, int K)
{
    __shared__ short As[BM * BK];
    __shared__ short Bs[BN * BK];

    const int tid  = threadIdx.x;
    const int wave = tid >> 6;
    const int lane = tid & 63;
    const int wm   = wave >> 1;
    const int wn   = wave & 1;
    const int l15  = lane & 15;
    const int quad = lane >> 4;

    const int nTilesN = N / BN;
    const int bm = blockIdx.x / nTilesN;
    const int bn = blockIdx.x % nTilesN;
    const int rowBase = bm * BM;
    const int colBase = bn * BN;
    const int srow = tid >> 3;
    const int scol = (tid & 7) * 8;
    const int groups = K >> 7;

    f32x4 acc[4][4];
    #pragma unroll
    for (int i = 0; i < 4; ++i)
        #pragma unroll
        for (int j = 0; j < 4; ++j)
            acc[i][j] = (f32x4){0.f, 0.f, 0.f, 0.f};

    float t_prev[4] = {1.f, 1.f, 1.f, 1.f};

    for (int k0 = 0; k0 < K; k0 += BK) {
        i32x4 ra[4], rb[4];
        #pragma unroll
        for (int i = 0; i < 4; ++i) {
            const int row = i * 32 + srow;
            const float* gA = Xf + (size_t)(rowBase + row) * K + (k0 + scol);
            const float* gB = Wf + (size_t)(colBase + row) * K + (k0 + scol);
            f32x4 a0 = *(const f32x4*)gA, a1 = *(const f32x4*)(gA + 4);
            f32x4 b0 = *(const f32x4*)gB, b1 = *(const f32x4*)(gB + 4);
            ra[i].x = pk_bf16_rne(a0.x, a0.y); ra[i].y = pk_bf16_rne(a0.z, a0.w);
            ra[i].z = pk_bf16_rne(a1.x, a1.y); ra[i].w = pk_bf16_rne(a1.z, a1.w);
            rb[i].x = pk_bf16_rne(b0.x, b0.y); rb[i].y = pk_bf16_rne(b0.z, b0.w);
            rb[i].z = pk_bf16_rne(b1.x, b1.y); rb[i].w = pk_bf16_rne(b1.z, b1.w);
        }
        if ((k0 & 127) == 0) {
            const int g = k0 >> 7;
            float r[4];
            #pragma unroll
            for (int nt = 0; nt < 4; ++nt) {
                const int o = colBase + wn * 64 + nt * 16 + l15;
                const float t_cur = S[(size_t)o * groups + g];
                r[nt] = t_prev[nt] / t_cur;
                t_prev[nt] = t_cur;
            }
            #pragma unroll
            for (int mt = 0; mt < 4; ++mt)
                #pragma unroll
                for (int nt = 0; nt < 4; ++nt)
                    #pragma unroll
                    for (int e = 0; e < 4; ++e)
                        acc[mt][nt][e] *= r[nt];
        }
        __syncthreads();
        #pragma unroll
        for (int i = 0; i < 4; ++i) {
            const int row = i * 32 + srow;
            *(i32x4*)&As[row * BK + scol] = ra[i];
            *(i32x4*)&Bs[row * BK + scol] = rb[i];
        }
        __syncthreads();
        #pragma unroll
        for (int ks = 0; ks < 2; ++ks) {
            const int kb = ks * 32 + quad * 8;
            bf16x8 a[4], b[4];
            #pragma unroll
            for (int t = 0; t < 4; ++t)
                a[t] = *(const bf16x8*)&As[(wm * 64 + t * 16 + l15) * BK + kb];
            #pragma unroll
            for (int t = 0; t < 4; ++t)
                b[t] = *(const bf16x8*)&Bs[(wn * 64 + t * 16 + l15) * BK + kb];
            #pragma unroll
            for (int mt = 0; mt < 4; ++mt)
                #pragma unroll
                for (int nt = 0; nt < 4; ++nt)
                    acc[mt][nt] = __builtin_amdgcn_mfma_f32_16x16x32_bf16(
                        a[mt], b[nt], acc[mt][nt], 0, 0, 0);
        }
    }
    #pragma unroll
    for (int nt = 0; nt < 4; ++nt) {
        const int col = colBase + wn * 64 + nt * 16 + l15;
        const float tl = t_prev[nt];
        const float bf = Bv[col];
        #pragma unroll
        for (int mt = 0; mt < 4; ++mt) {
            const int row0 = rowBase + wm * 64 + mt * 16 + quad * 4;
            #pragma unroll
            for (int r = 0; r < 4; ++r)
                Y[(size_t)(row0 + r) * N + col] = acc[mt][nt][r] * tl + bf;
        }
    }
}

extern "C" void kernel_launch(void* const* d_in, const int* in_sizes, int n_in,
                              void* d_out, int out_size, void* d_ws, size_t ws_size,
                              hipStream_t stream) {
    const float* X  = (const float*)d_in[0];   // x      (B,S,I)  f32
    const float* W  = (const float*)d_in[1];   // weight (O,I)    f32
    const float* S  = (const float*)d_in[2];   // scales (O,I/G)  f32
    const float* Bv = (const float*)d_in[3];   // bias   (O,)     f32
    float* Y = (float*)d_out;

    const int O = in_sizes[3];                 // 4096
    const int K = in_sizes[1] / O;             // 4096
    const int M = in_sizes[0] / K;             // 8192

    const dim3 grid((M / BM) * (O / BN));
    const size_t nX = (size_t)M * K, nW = (size_t)O * K;
    const size_t wsNeeded = (nX + nW) * sizeof(unsigned short);

    if (ws_size >= wsNeeded) {
        unsigned short* Xb = (unsigned short*)d_ws;
        unsigned short* Wb = Xb + nX;
        cvt_f32_bf16<<<(int)(nX >> 11), 256, 0, stream>>>(X, Xb, (long)nX);  // 1 grp/thread
        cvt_f32_bf16<<<(int)(nW >> 11), 256, 0, stream>>>(W, Wb, (long)nW);
        gq_gemm_lds<<<grid, 256, 0, stream>>>(Xb, Wb, S, Bv, Y, M, O, K);
    } else {
        gq_gemm_f32in<<<grid, 256, 0, stream>>>(X, W, S, Bv, Y, M, O, K);
    }
}

// Round 6
// 664.300 us; speedup vs baseline: 1.1578x; 1.1034x over previous
//
#include <hip/hip_runtime.h>
#include <hip/hip_bf16.h>

// Grouped-dequant GEMM: Y[m,o] = sum_k X[m,k] * W[o,k] * S[o, k/128] + bias[o]
// M=8192, N=O=4096, K=I=4096, G=128. Harness promotes fp16 tensors to f32.
// Path A: f32->bf16 convert into d_ws, then m97-structure GEMM with XOR-swizzled
// LDS chunks: slot(r, c) holds global chunk c ^ (r&7). This spreads the
// ds_read_b128 fragment reads over all 32 banks (R5 showed 1.007e8 conflict
// cycles = 32% of kernel time from quad-only bank addressing).
// DMA staging keeps coalescing: lane l fetches global chunk (l&7)^(l>>3).

typedef short bf16x8 __attribute__((ext_vector_type(8)));
typedef float f32x4 __attribute__((ext_vector_type(4)));
typedef int   i32x4 __attribute__((ext_vector_type(4)));

#define BM 128
#define BN 128
#define BK 64

__device__ __forceinline__ unsigned pk_bf16_rne(float x, float y) {
    unsigned a = __float_as_uint(x), b = __float_as_uint(y);
    a = a + 0x7FFFu + ((a >> 16) & 1u);          // round-to-nearest-even
    b = b + 0x7FFFu + ((b >> 16) & 1u);
    return (b & 0xFFFF0000u) | (a >> 16);
}

// ---- f32 -> bf16 bulk convert (8 f32 -> 16B per thread) ----
__global__ __launch_bounds__(256) void cvt_f32_bf16(
    const float* __restrict__ src, unsigned short* __restrict__ dst, long n)
{
    long i = (long)(blockIdx.x) * blockDim.x + threadIdx.x;   // units of 8 elts
    const long n8 = n >> 3;
    const long stride = (long)gridDim.x * blockDim.x;
    for (; i < n8; i += stride) {
        f32x4 a = *(const f32x4*)(src + i * 8);
        f32x4 b = *(const f32x4*)(src + i * 8 + 4);
        i32x4 o;
        o.x = pk_bf16_rne(a.x, a.y);
        o.y = pk_bf16_rne(a.z, a.w);
        o.z = pk_bf16_rne(b.x, b.y);
        o.w = pk_bf16_rne(b.z, b.w);
        *(i32x4*)(dst + i * 8) = o;
    }
}

// ---- Path A GEMM: bf16 inputs, DMA staging, XOR-swizzled LDS ----
__global__ __launch_bounds__(256) void gq_gemm_lds(
    const unsigned short* __restrict__ X,    // M x K  bf16 bits
    const unsigned short* __restrict__ W,    // N x K  bf16 bits
    const float* __restrict__ S,             // N x (K/128)
    const float* __restrict__ Bv,            // N
    float* __restrict__ Y,                   // M x N  f32
    int M, int N, int K)
{
    __shared__ short As[BM * BK];   // [row][8 chunks of 8 shorts], chunk-swizzled
    __shared__ short Bs[BN * BK];

    const int tid  = threadIdx.x;
    const int wave = tid >> 6;
    const int lane = tid & 63;
    const int wm   = wave >> 1;
    const int wn   = wave & 1;
    const int l15  = lane & 15;
    const int quad = lane >> 4;
    const int sw   = l15 & 7;       // row-derived swizzle key for fragment reads

    const int nTilesN = N / BN;
    const int bm = blockIdx.x / nTilesN;
    const int bn = blockIdx.x % nTilesN;
    const int rowBase = bm * BM;
    const int colBase = bn * BN;

    // staging: lane l covers row offset l>>3; fetches global chunk (l&7)^(l>>3)
    // so that LDS slot (r, c) = global chunk c ^ (r&7). DMA writes base+lane*16.
    const int lrow = lane >> 3;                       // 0..7
    const int lcol = ((lane & 7) ^ lrow) * 8;         // swizzled global source

    const int groups = K >> 7;

    f32x4 acc[4][4];
    #pragma unroll
    for (int i = 0; i < 4; ++i)
        #pragma unroll
        for (int j = 0; j < 4; ++j)
            acc[i][j] = (f32x4){0.f, 0.f, 0.f, 0.f};

    float t_prev[4] = {1.f, 1.f, 1.f, 1.f};

    for (int k0 = 0; k0 < K; k0 += BK) {
        __syncthreads();            // all waves done reading prev tile's LDS

        #pragma unroll
        for (int i = 0; i < 4; ++i) {
            const int row = i * 32 + wave * 8 + lrow;
            const unsigned short* gA = X + (size_t)(rowBase + row) * K + (k0 + lcol);
            const unsigned short* gB = W + (size_t)(colBase + row) * K + (k0 + lcol);
            short* lA = &As[(i * 32 + wave * 8) * BK];   // wave-uniform base
            short* lB = &Bs[(i * 32 + wave * 8) * BK];
            __builtin_amdgcn_global_load_lds(
                (const __attribute__((address_space(1))) void*)gA,
                (__attribute__((address_space(3))) void*)lA, 16, 0, 0);
            __builtin_amdgcn_global_load_lds(
                (const __attribute__((address_space(1))) void*)gB,
                (__attribute__((address_space(3))) void*)lB, 16, 0, 0);
        }

        // ---- group boundary: telescoping rescale acc *= t_prev / t_cur ----
        if ((k0 & 127) == 0) {
            const int g = k0 >> 7;
            float r[4];
            #pragma unroll
            for (int nt = 0; nt < 4; ++nt) {
                const int o = colBase + wn * 64 + nt * 16 + l15;
                const float t_cur = S[(size_t)o * groups + g];
                r[nt] = t_prev[nt] / t_cur;
                t_prev[nt] = t_cur;
            }
            #pragma unroll
            for (int mt = 0; mt < 4; ++mt)
                #pragma unroll
                for (int nt = 0; nt < 4; ++nt)
                    #pragma unroll
                    for (int e = 0; e < 4; ++e)
                        acc[mt][nt][e] *= r[nt];
        }

        __syncthreads();            // barrier's vmcnt(0) drains the DMA

        // ---- compute: 2 k-steps of 32, 16 MFMAs each ----
        #pragma unroll
        for (int ks = 0; ks < 2; ++ks) {
            const int kb = ((ks * 4 + quad) ^ sw) * 8;   // swizzled chunk slot
            bf16x8 a[4], b[4];
            #pragma unroll
            for (int t = 0; t < 4; ++t)
                a[t] = *(const bf16x8*)&As[(wm * 64 + t * 16 + l15) * BK + kb];
            #pragma unroll
            for (int t = 0; t < 4; ++t)
                b[t] = *(const bf16x8*)&Bs[(wn * 64 + t * 16 + l15) * BK + kb];
            #pragma unroll
            for (int mt = 0; mt < 4; ++mt)
                #pragma unroll
                for (int nt = 0; nt < 4; ++nt)
                    acc[mt][nt] = __builtin_amdgcn_mfma_f32_16x16x32_bf16(
                        a[mt], b[nt], acc[mt][nt], 0, 0, 0);
        }
    }

    // ---- epilogue: Y = acc * t_last + bias ----
    #pragma unroll
    for (int nt = 0; nt < 4; ++nt) {
        const int col = colBase + wn * 64 + nt * 16 + l15;
        const float tl = t_prev[nt];
        const float bf = Bv[col];
        #pragma unroll
        for (int mt = 0; mt < 4; ++mt) {
            const int row0 = rowBase + wm * 64 + mt * 16 + quad * 4;
            #pragma unroll
            for (int r = 0; r < 4; ++r)
                Y[(size_t)(row0 + r) * N + col] = acc[mt][nt][r] * tl + bf;
        }
    }
}

// ---- Path B fallback: f32 inputs inline-converted, swizzled ds_write staging ----
__global__ __launch_bounds__(256) void gq_gemm_f32in(
    const float* __restrict__ Xf, const float* __restrict__ Wf,
    const float* __restrict__ S, const float* __restrict__ Bv,
    float* __restrict__ Y, int M, int N, int K)
{
    __shared__ short As[BM * BK];
    __shared__ short Bs[BN * BK];

    const int tid  = threadIdx.x;
    const int wave = tid >> 6;
    const int lane = tid & 63;
    const int wm   = wave >> 1;
    const int wn   = wave & 1;
    const int l15  = lane & 15;
    const int quad = lane >> 4;
    const int sw   = l15 & 7;

    const int nTilesN = N / BN;
    const int bm = blockIdx.x / nTilesN;
    const int bn = blockIdx.x % nTilesN;
    const int rowBase = bm * BM;
    const int colBase = bn * BN;
    const int srow  = tid >> 3;                       // 0..31
    const int scol  = (tid & 7) * 8;                  // sequential global source
    const int sslot = ((tid & 7) ^ (srow & 7)) * 8;   // swizzled LDS dest
    const int groups = K >> 7;

    f32x4 acc[4][4];
    #pragma unroll
    for (int i = 0; i < 4; ++i)
        #pragma unroll
        for (int j = 0; j < 4; ++j)
            acc[i][j] = (f32x4){0.f, 0.f, 0.f, 0.f};

    float t_prev[4] = {1.f, 1.f, 1.f, 1.f};

    for (int k0 = 0; k0 < K; k0 += BK) {
        i32x4 ra[4], rb[4];
        #pragma unroll
        for (int i = 0; i < 4; ++i) {
            const int row = i * 32 + srow;
            const float* gA = Xf + (size_t)(rowBase + row) * K + (k0 + scol);
            const float* gB = Wf + (size_t)(colBase + row) * K + (k0 + scol);
            f32x4 a0 = *(const f32x4*)gA, a1 = *(const f32x4*)(gA + 4);
            f32x4 b0 = *(const f32x4*)gB, b1 = *(const f32x4*)(gB + 4);
            ra[i].x = pk_bf16_rne(a0.x, a0.y); ra[i].y = pk_bf16_rne(a0.z, a0.w);
            ra[i].z = pk_bf16_rne(a1.x, a1.y); ra[i].w = pk_bf16_rne(a1.z, a1.w);
            rb[i].x = pk_bf16_rne(b0.x, b0.y); rb[i].y = pk_bf16_rne(b0.z, b0.w);
            rb[i].z = pk_bf16_rne(b1.x, b1.y); rb[i].w = pk_bf16_rne(b1.z, b1.w);
        }
        if ((k0 & 127) == 0) {
            const int g = k0 >> 7;
            float r[4];
            #pragma unroll
            for (int nt = 0; nt < 4; ++nt) {
                const int o = colBase + wn * 64 + nt * 16 + l15;
                const float t_cur = S[(size_t)o * groups + g];
                r[nt] = t_prev[nt] / t_cur;
                t_prev[nt] = t_cur;
            }
            #pragma unroll
            for (int mt = 0; mt < 4; ++mt)
                #pragma unroll
                for (int nt = 0; nt < 4; ++nt)
                    #pragma unroll
                    for (int e = 0; e < 4; ++e)
                        acc[mt][nt][e] *= r[nt];
        }
        __syncthreads();
        #pragma unroll
        for (int i = 0; i < 4; ++i) {
            const int row = i * 32 + srow;
            *(i32x4*)&As[row * BK + sslot] = ra[i];
            *(i32x4*)&Bs[row * BK + sslot] = rb[i];
        }
        __syncthreads();
        #pragma unroll
        for (int ks = 0; ks < 2; ++ks) {
            const int kb = ((ks * 4 + quad) ^ sw) * 8;
            bf16x8 a[4], b[4];
            #pragma unroll
            for (int t = 0; t < 4; ++t)
                a[t] = *(const bf16x8*)&As[(wm * 64 + t * 16 + l15) * BK + kb];
            #pragma unroll
            for (int t = 0; t < 4; ++t)
                b[t] = *(const bf16x8*)&Bs[(wn * 64 + t * 16 + l15) * BK + kb];
            #pragma unroll
            for (int mt = 0; mt < 4; ++mt)
                #pragma unroll
                for (int nt = 0; nt < 4; ++nt)
                    acc[mt][nt] = __builtin_amdgcn_mfma_f32_16x16x32_bf16(
                        a[mt], b[nt], acc[mt][nt], 0, 0, 0);
        }
    }
    #pragma unroll
    for (int nt = 0; nt < 4; ++nt) {
        const int col = colBase + wn * 64 + nt * 16 + l15;
        const float tl = t_prev[nt];
        const float bf = Bv[col];
        #pragma unroll
        for (int mt = 0; mt < 4; ++mt) {
            const int row0 = rowBase + wm * 64 + mt * 16 + quad * 4;
            #pragma unroll
            for (int r = 0; r < 4; ++r)
                Y[(size_t)(row0 + r) * N + col] = acc[mt][nt][r] * tl + bf;
        }
    }
}

extern "C" void kernel_launch(void* const* d_in, const int* in_sizes, int n_in,
                              void* d_out, int out_size, void* d_ws, size_t ws_size,
                              hipStream_t stream) {
    const float* X  = (const float*)d_in[0];   // x      (B,S,I)  f32
    const float* W  = (const float*)d_in[1];   // weight (O,I)    f32
    const float* S  = (const float*)d_in[2];   // scales (O,I/G)  f32
    const float* Bv = (const float*)d_in[3];   // bias   (O,)     f32
    float* Y = (float*)d_out;

    const int O = in_sizes[3];                 // 4096
    const int K = in_sizes[1] / O;             // 4096
    const int M = in_sizes[0] / K;             // 8192

    const dim3 grid((M / BM) * (O / BN));
    const size_t nX = (size_t)M * K, nW = (size_t)O * K;
    const size_t wsNeeded = (nX + nW) * sizeof(unsigned short);

    if (ws_size >= wsNeeded) {
        unsigned short* Xb = (unsigned short*)d_ws;
        unsigned short* Wb = Xb + nX;
        cvt_f32_bf16<<<(int)(nX >> 11), 256, 0, stream>>>(X, Xb, (long)nX);
        cvt_f32_bf16<<<(int)(nW >> 11), 256, 0, stream>>>(W, Wb, (long)nW);
        gq_gemm_lds<<<grid, 256, 0, stream>>>(Xb, Wb, S, Bv, Y, M, O, K);
    } else {
        gq_gemm_f32in<<<grid, 256, 0, stream>>>(X, W, S, Bv, Y, M, O, K);
    }
}